// Round 1
// baseline (123.326 us; speedup 1.0000x reference)
//
#include <hip/hip_runtime.h>

#define HH 480
#define WW 640
#define NPIX (HH * WW)
#define BB 16
#define PPT 8                      // pixels per thread (one row segment)
#define BLK 256
#define GX (NPIX / (BLK * PPT))    // 150 tiles along pixel dim
#define NPART (GX * BB * 2)        // 4800 block partials
#define NXCD 8

typedef float vf2 __attribute__((ext_vector_type(2)));
struct __attribute__((packed, aligned(4))) uf2 { vf2 v; };

// 1D grid of 4800 blocks. XCD-aware decode: hardware round-robins linear
// block id across the 8 XCDs (id % 8 == XCD). Pin batch b to XCD (b % 8)
// so both its images (gather targets of the two passes, 1.2 MB each) are
// fetched into exactly ONE XCD's L2 instead of being replicated 8x.
//   id = 0..4799 ; xcd = id & 7 ; slot = id >> 3 (0..599)
//   b    = xcd + 8*(slot & 1)        -> 2 batches per XCD
//   pass = (slot >> 1) & 1
//   tile = slot >> 2                 (0..149)
__global__ __launch_bounds__(BLK) void proj_depth_loss_kernel(
    const float* __restrict__ depth0, const float* __restrict__ depth1,
    const float* __restrict__ R0, const float* __restrict__ t0,
    const float* __restrict__ R1, const float* __restrict__ t1,
    const float* __restrict__ Km,
    float* __restrict__ partials)
{
    const int id   = blockIdx.x;
    const int xcd  = id & (NXCD - 1);
    const int slot = id >> 3;
    const int b    = xcd + ((slot & 1) << 3);
    const int pass = (slot >> 1) & 1;
    const int tile = slot >> 2;
    const int n0 = (tile * BLK + threadIdx.x) * PPT;

    const float* Ds = (pass == 0) ? depth0 : depth1;
    const float* Dt = (pass == 0) ? depth1 : depth0;
    const float* Ra = (pass == 0) ? R0 : R1;
    const float* ta = (pass == 0) ? t0 : t1;
    const float* Rb = (pass == 0) ? R1 : R0;
    const float* tb = (pass == 0) ? t1 : t0;

    // uvd = d * (Mq (u,v,1)) + c
    // Mq = K Rb Ra^T Ki (rows 0/1 pre-scaled by W/(W-1), H/(H-1)),
    // c  = K (tb - Rb Ra^T ta), Ki = [[s,0,-320s],[0,s,-240s],[0,0,1]], s=1/500.
    const float* A = Ra + b * 9;
    const float* Bm = Rb + b * 9;
    float N_[9];  // N = Rb * Ra^T
    #pragma unroll
    for (int i = 0; i < 3; ++i)
        #pragma unroll
        for (int jj = 0; jj < 3; ++jj)
            N_[i*3+jj] = Bm[i*3+0]*A[jj*3+0] + Bm[i*3+1]*A[jj*3+1] + Bm[i*3+2]*A[jj*3+2];
    float tax=ta[b*3+0], tay=ta[b*3+1], taz=ta[b*3+2];
    float qx_ = tb[b*3+0] - (N_[0]*tax + N_[1]*tay + N_[2]*taz);
    float qy_ = tb[b*3+1] - (N_[3]*tax + N_[4]*tay + N_[5]*taz);
    float qz_ = tb[b*3+2] - (N_[6]*tax + N_[7]*tay + N_[8]*taz);
    float M_[9];
    #pragma unroll
    for (int i = 0; i < 3; ++i)
        #pragma unroll
        for (int jj = 0; jj < 3; ++jj)
            M_[i*3+jj] = Km[i*3+0]*N_[0*3+jj] + Km[i*3+1]*N_[1*3+jj] + Km[i*3+2]*N_[2*3+jj];
    float cx = Km[0]*qx_ + Km[1]*qy_ + Km[2]*qz_;
    float cy = Km[3]*qx_ + Km[4]*qy_ + Km[5]*qz_;
    float cz = Km[6]*qx_ + Km[7]*qy_ + Km[8]*qz_;

    const float s_ = 1.0f / 500.0f;
    const float cwf = (float)WW / (float)(WW - 1);
    const float chf = (float)HH / (float)(HH - 1);
    float Mq[9];
    #pragma unroll
    for (int i = 0; i < 3; ++i) {
        float r0 = M_[i*3+0] * s_;
        float r1 = M_[i*3+1] * s_;
        float r2 = M_[i*3+0] * (-320.0f * s_) + M_[i*3+1] * (-240.0f * s_) + M_[i*3+2];
        float sc = (i == 0) ? cwf : (i == 1) ? chf : 1.0f;
        Mq[i*3+0] = r0 * sc; Mq[i*3+1] = r1 * sc; Mq[i*3+2] = r2 * sc;
    }
    float cxs = cx * cwf, cys = cy * chf;

    // coalesced source depth: 8 floats, regular cached loads (this image
    // is the gather target of the opposite pass — keep it in L2)
    const float4* dp = (const float4*)(Ds + (size_t)b * NPIX + n0);
    float4 da = dp[0], db = dp[1];
    float dd[PPT] = {da.x, da.y, da.z, da.w, db.x, db.y, db.z, db.w};

    const int vrow = n0 / WW;            // all PPT px in same row (W % PPT == 0)
    const float fv = (float)vrow;
    const float fu0 = (float)(n0 - vrow * WW);

    // hoist the v-dependent part of the projection
    float bxv = fmaf(Mq[1], fv, Mq[2]);
    float byv = fmaf(Mq[4], fv, Mq[5]);
    float bzv = fmaf(Mq[7], fv, Mq[8]);

    float ud[PPT], wxs[PPT], wyf[PPT];
    int base[PPT], dy1[PPT];

    #pragma unroll
    for (int i = 0; i < PPT; ++i) {
        float fu = fu0 + (float)i;
        float mrx = fmaf(Mq[0], fu, bxv);
        float mry = fmaf(Mq[3], fu, byv);
        float mrz = fmaf(Mq[6], fu, bzv);
        float ux = fmaf(dd[i], mrx, cxs);
        float uy = fmaf(dd[i], mry, cys);
        float uu = fmaf(dd[i], mrz, cz);
        ud[i] = uu;

        float inv = __builtin_amdgcn_rcpf(fmaxf(uu, 0.0f) + 1e-12f);
        float sx = fmaf(ux, inv, -0.5f);
        float sy = fmaf(uy, inv, -0.5f);
        sx = fminf(fmaxf(sx, 0.0f), (float)(WW - 1));
        sy = fminf(fmaxf(sy, 0.0f), (float)(HH - 1));
        float fx0 = floorf(sx);
        float fy0 = floorf(sy);
        float wxf = sx - fx0;
        wyf[i] = sy - fy0;
        int x0 = (int)fx0;
        int y0 = (int)fy0;
        // Pair-load trick: one dwordx2 fetches {img[p], img[p+1]}.
        // x0==W-1 implies wxf==0; shift window left 1, force weight 1.0.
        int atEdge = (x0 == WW - 1);
        base[i] = y0 * WW + x0 - atEdge;
        wxs[i] = atEdge ? 1.0f : wxf;
        dy1[i] = (y0 < HH - 1) ? WW : 0;
    }

    const float* img = Dt + (size_t)b * NPIX;
    vf2 top[PPT], bot[PPT];
    #pragma unroll
    for (int i = 0; i < PPT; ++i) {
        top[i] = ((const uf2*)(img + base[i]))->v;            // {v00, v01}
        bot[i] = ((const uf2*)(img + base[i] + dy1[i]))->v;   // {v10, v11}
    }

    float diff = 0.0f;
    #pragma unroll
    for (int i = 0; i < PPT; ++i) {
        float tv = top[i].x + wxs[i] * (top[i].y - top[i].x);
        float bv = bot[i].x + wxs[i] * (bot[i].y - bot[i].x);
        float s = tv + wyf[i] * (bv - tv);
        diff += fabsf(ud[i] - s);
    }

    for (int off = 32; off > 0; off >>= 1)
        diff += __shfl_down(diff, off, 64);

    __shared__ float partial[BLK / 64];
    const int wave = threadIdx.x >> 6;
    const int lane = threadIdx.x & 63;
    if (lane == 0) partial[wave] = diff;
    __syncthreads();
    if (threadIdx.x == 0) {
        float s = partial[0] + partial[1] + partial[2] + partial[3];
        partials[id] = s;
    }
}

__global__ __launch_bounds__(1024) void reduce_partials_kernel(
    const float* __restrict__ partials, float* __restrict__ out)
{
    float s = 0.0f;
    for (int i = threadIdx.x; i < NPART; i += 1024) s += partials[i];
    for (int off = 32; off > 0; off >>= 1)
        s += __shfl_down(s, off, 64);
    __shared__ float partial[16];
    const int wave = threadIdx.x >> 6;
    const int lane = threadIdx.x & 63;
    if (lane == 0) partial[wave] = s;
    __syncthreads();
    if (threadIdx.x == 0) {
        float tot = 0.0f;
        #pragma unroll
        for (int i = 0; i < 16; ++i) tot += partial[i];
        out[0] = tot * (1.0f / (float)((long long)BB * NPIX));
    }
}

extern "C" void kernel_launch(void* const* d_in, const int* in_sizes, int n_in,
                              void* d_out, int out_size, void* d_ws, size_t ws_size,
                              hipStream_t stream) {
    const float* depth0 = (const float*)d_in[0];
    const float* depth1 = (const float*)d_in[1];
    const float* R0     = (const float*)d_in[2];
    const float* t0     = (const float*)d_in[3];
    const float* R1     = (const float*)d_in[4];
    const float* t1     = (const float*)d_in[5];
    const float* Km     = (const float*)d_in[6];
    float* out = (float*)d_out;
    float* partials = (float*)d_ws;

    proj_depth_loss_kernel<<<dim3(NPART), dim3(BLK), 0, stream>>>(
        depth0, depth1, R0, t0, R1, t1, Km, partials);
    reduce_partials_kernel<<<1, 1024, 0, stream>>>(partials, out);
}

// Round 2
// 117.073 us; speedup vs baseline: 1.0534x; 1.0534x over previous
//
#include <hip/hip_runtime.h>

#define HH 480
#define WW 640
#define NPIX (HH * WW)
#define BB 16
#define PPT 8                      // pixels per thread (one row segment)
#define BLK 256
#define GX (NPIX / (BLK * PPT))    // 150 tiles along pixel dim
#define NPART (GX * BB * 2)        // 4800 block partials
#define NXCD 8

typedef float vf2 __attribute__((ext_vector_type(2)));
struct __attribute__((packed, aligned(4))) uf2 { vf2 v; };

// 1D grid of 4800 blocks, id round-robins across XCDs (id % 8 == XCD).
// Pin batch b to XCD (b % 8), but SERIALIZE the 4 (b,pass) pairs in time
// (tile fastest-varying), ordered so consecutive pairs share the same two
// images:
//   q=0: (b=x,  pass0)  src d0[x]   -> gather d1[x]
//   q=1: (b=x,  pass1)  src d1[x]   -> gather d0[x]   (same 2 images!)
//   q=2: (b=x+8,pass0)  src d0[x+8] -> gather d1[x+8]
//   q=3: (b=x+8,pass1)  src d1[x+8] -> gather d0[x+8]
// Live working set per XCD L2 = ~2.4 MB (2 images) < 4 MiB, each image
// filled into exactly one L2 and reused as source AND gather target.
// (R1's interleaved decode kept 4 images live -> L2 thrash -> regression.)
__global__ __launch_bounds__(BLK) void proj_depth_loss_kernel(
    const float* __restrict__ depth0, const float* __restrict__ depth1,
    const float* __restrict__ R0, const float* __restrict__ t0,
    const float* __restrict__ R1, const float* __restrict__ t1,
    const float* __restrict__ Km,
    float* __restrict__ partials)
{
    const int id   = blockIdx.x;
    const int xcd  = id & (NXCD - 1);
    const int slot = id >> 3;          // 0..599
    const int q    = slot / GX;        // 0..3 pair index (slowest)
    const int tile = slot - q * GX;    // 0..149 (fastest)
    const int b    = xcd + ((q >> 1) << 3);
    const int pass = q & 1;
    const int n0 = (tile * BLK + threadIdx.x) * PPT;

    const float* Ds = (pass == 0) ? depth0 : depth1;
    const float* Dt = (pass == 0) ? depth1 : depth0;
    const float* Ra = (pass == 0) ? R0 : R1;
    const float* ta = (pass == 0) ? t0 : t1;
    const float* Rb = (pass == 0) ? R1 : R0;
    const float* tb = (pass == 0) ? t1 : t0;

    // uvd = d * (Mq (u,v,1)) + c
    // Mq = K Rb Ra^T Ki (rows 0/1 pre-scaled by W/(W-1), H/(H-1)),
    // c  = K (tb - Rb Ra^T ta), Ki = [[s,0,-320s],[0,s,-240s],[0,0,1]], s=1/500.
    const float* A = Ra + b * 9;
    const float* Bm = Rb + b * 9;
    float N_[9];  // N = Rb * Ra^T
    #pragma unroll
    for (int i = 0; i < 3; ++i)
        #pragma unroll
        for (int jj = 0; jj < 3; ++jj)
            N_[i*3+jj] = Bm[i*3+0]*A[jj*3+0] + Bm[i*3+1]*A[jj*3+1] + Bm[i*3+2]*A[jj*3+2];
    float tax=ta[b*3+0], tay=ta[b*3+1], taz=ta[b*3+2];
    float qx_ = tb[b*3+0] - (N_[0]*tax + N_[1]*tay + N_[2]*taz);
    float qy_ = tb[b*3+1] - (N_[3]*tax + N_[4]*tay + N_[5]*taz);
    float qz_ = tb[b*3+2] - (N_[6]*tax + N_[7]*tay + N_[8]*taz);
    float M_[9];
    #pragma unroll
    for (int i = 0; i < 3; ++i)
        #pragma unroll
        for (int jj = 0; jj < 3; ++jj)
            M_[i*3+jj] = Km[i*3+0]*N_[0*3+jj] + Km[i*3+1]*N_[1*3+jj] + Km[i*3+2]*N_[2*3+jj];
    float cx = Km[0]*qx_ + Km[1]*qy_ + Km[2]*qz_;
    float cy = Km[3]*qx_ + Km[4]*qy_ + Km[5]*qz_;
    float cz = Km[6]*qx_ + Km[7]*qy_ + Km[8]*qz_;

    const float s_ = 1.0f / 500.0f;
    const float cwf = (float)WW / (float)(WW - 1);
    const float chf = (float)HH / (float)(HH - 1);
    float Mq[9];
    #pragma unroll
    for (int i = 0; i < 3; ++i) {
        float r0 = M_[i*3+0] * s_;
        float r1 = M_[i*3+1] * s_;
        float r2 = M_[i*3+0] * (-320.0f * s_) + M_[i*3+1] * (-240.0f * s_) + M_[i*3+2];
        float sc = (i == 0) ? cwf : (i == 1) ? chf : 1.0f;
        Mq[i*3+0] = r0 * sc; Mq[i*3+1] = r1 * sc; Mq[i*3+2] = r2 * sc;
    }
    float cxs = cx * cwf, cys = cy * chf;

    // coalesced source depth: 8 floats, regular cached loads (this image
    // is the gather target of the next pair on this XCD — keep it in L2)
    const float4* dp = (const float4*)(Ds + (size_t)b * NPIX + n0);
    float4 da = dp[0], db = dp[1];
    float dd[PPT] = {da.x, da.y, da.z, da.w, db.x, db.y, db.z, db.w};

    const int vrow = n0 / WW;            // all PPT px in same row (W % PPT == 0)
    const float fv = (float)vrow;
    const float fu0 = (float)(n0 - vrow * WW);

    // hoist the v-dependent part of the projection
    float bxv = fmaf(Mq[1], fv, Mq[2]);
    float byv = fmaf(Mq[4], fv, Mq[5]);
    float bzv = fmaf(Mq[7], fv, Mq[8]);

    float ud[PPT], wxs[PPT], wyf[PPT];
    int base[PPT], dy1[PPT];

    #pragma unroll
    for (int i = 0; i < PPT; ++i) {
        float fu = fu0 + (float)i;
        float mrx = fmaf(Mq[0], fu, bxv);
        float mry = fmaf(Mq[3], fu, byv);
        float mrz = fmaf(Mq[6], fu, bzv);
        float ux = fmaf(dd[i], mrx, cxs);
        float uy = fmaf(dd[i], mry, cys);
        float uu = fmaf(dd[i], mrz, cz);
        ud[i] = uu;

        float inv = __builtin_amdgcn_rcpf(fmaxf(uu, 0.0f) + 1e-12f);
        float sx = fmaf(ux, inv, -0.5f);
        float sy = fmaf(uy, inv, -0.5f);
        sx = fminf(fmaxf(sx, 0.0f), (float)(WW - 1));
        sy = fminf(fmaxf(sy, 0.0f), (float)(HH - 1));
        float fx0 = floorf(sx);
        float fy0 = floorf(sy);
        float wxf = sx - fx0;
        wyf[i] = sy - fy0;
        int x0 = (int)fx0;
        int y0 = (int)fy0;
        // Pair-load trick: one dwordx2 fetches {img[p], img[p+1]}.
        // x0==W-1 implies wxf==0; shift window left 1, force weight 1.0.
        int atEdge = (x0 == WW - 1);
        base[i] = y0 * WW + x0 - atEdge;
        wxs[i] = atEdge ? 1.0f : wxf;
        dy1[i] = (y0 < HH - 1) ? WW : 0;
    }

    const float* img = Dt + (size_t)b * NPIX;
    vf2 top[PPT], bot[PPT];
    #pragma unroll
    for (int i = 0; i < PPT; ++i) {
        top[i] = ((const uf2*)(img + base[i]))->v;            // {v00, v01}
        bot[i] = ((const uf2*)(img + base[i] + dy1[i]))->v;   // {v10, v11}
    }

    float diff = 0.0f;
    #pragma unroll
    for (int i = 0; i < PPT; ++i) {
        float tv = top[i].x + wxs[i] * (top[i].y - top[i].x);
        float bv = bot[i].x + wxs[i] * (bot[i].y - bot[i].x);
        float s = tv + wyf[i] * (bv - tv);
        diff += fabsf(ud[i] - s);
    }

    for (int off = 32; off > 0; off >>= 1)
        diff += __shfl_down(diff, off, 64);

    __shared__ float partial[BLK / 64];
    const int wave = threadIdx.x >> 6;
    const int lane = threadIdx.x & 63;
    if (lane == 0) partial[wave] = diff;
    __syncthreads();
    if (threadIdx.x == 0) {
        float s = partial[0] + partial[1] + partial[2] + partial[3];
        partials[id] = s;
    }
}

__global__ __launch_bounds__(1024) void reduce_partials_kernel(
    const float* __restrict__ partials, float* __restrict__ out)
{
    float s = 0.0f;
    for (int i = threadIdx.x; i < NPART; i += 1024) s += partials[i];
    for (int off = 32; off > 0; off >>= 1)
        s += __shfl_down(s, off, 64);
    __shared__ float partial[16];
    const int wave = threadIdx.x >> 6;
    const int lane = threadIdx.x & 63;
    if (lane == 0) partial[wave] = s;
    __syncthreads();
    if (threadIdx.x == 0) {
        float tot = 0.0f;
        #pragma unroll
        for (int i = 0; i < 16; ++i) tot += partial[i];
        out[0] = tot * (1.0f / (float)((long long)BB * NPIX));
    }
}

extern "C" void kernel_launch(void* const* d_in, const int* in_sizes, int n_in,
                              void* d_out, int out_size, void* d_ws, size_t ws_size,
                              hipStream_t stream) {
    const float* depth0 = (const float*)d_in[0];
    const float* depth1 = (const float*)d_in[1];
    const float* R0     = (const float*)d_in[2];
    const float* t0     = (const float*)d_in[3];
    const float* R1     = (const float*)d_in[4];
    const float* t1     = (const float*)d_in[5];
    const float* Km     = (const float*)d_in[6];
    float* out = (float*)d_out;
    float* partials = (float*)d_ws;

    proj_depth_loss_kernel<<<dim3(NPART), dim3(BLK), 0, stream>>>(
        depth0, depth1, R0, t0, R1, t1, Km, partials);
    reduce_partials_kernel<<<1, 1024, 0, stream>>>(partials, out);
}

// Round 4
// 110.948 us; speedup vs baseline: 1.1116x; 1.0552x over previous
//
#include <hip/hip_runtime.h>

#define HH 480
#define WW 640
#define NPIX (HH * WW)
#define BB 16
#define PPT 8                      // pixels per thread (one row segment)
#define BLK 256
#define GX (NPIX / (BLK * PPT))    // 150 blocks along pixel dim
#define NPART (GX * BB * 2)        // 4800 block partials

typedef float vf2 __attribute__((ext_vector_type(2)));
struct __attribute__((packed, aligned(4))) uf2 { vf2 v; };

// Grid: (GX, BB, 2) — R0's balanced spray (pairs serialized in dispatch
// order, blocks of each pair spread across all XCDs; measured best).
//
// OOB fast path: uu = d*mrz + cz with cz ~ N(0,~3) per (b,pass) and
// |d*mrz| ~ O(1) -> sign(uu) is mostly uniform per pair; ~half of all
// lanes project behind the camera, clamp to a CORNER of the target, and
// would spend TA/address-processing on gathers of 12 known floats.
// Preload the 6 border pairs once (wave-uniform, L1), classify with a
// conservative predicate (uu<=0 && |ux|>1 && |uy|>1 guarantees corner
// after the 1e12*ux clamp; borderline lanes fall back to real loads),
// and skip both gathers for corner lanes via exec-mask predication.
// Weights the load path computes for corner lanes are exactly {0,1}/0,
// so register-selected pairs give bit-identical results.
__global__ __launch_bounds__(BLK) void proj_depth_loss_kernel(
    const float* __restrict__ depth0, const float* __restrict__ depth1,
    const float* __restrict__ R0, const float* __restrict__ t0,
    const float* __restrict__ R1, const float* __restrict__ t1,
    const float* __restrict__ Km,
    float* __restrict__ partials)
{
    const int pass = blockIdx.z;
    const int b = blockIdx.y;
    const int n0 = (blockIdx.x * BLK + threadIdx.x) * PPT;

    const float* Ds = (pass == 0) ? depth0 : depth1;
    const float* Dt = (pass == 0) ? depth1 : depth0;
    const float* Ra = (pass == 0) ? R0 : R1;
    const float* ta = (pass == 0) ? t0 : t1;
    const float* Rb = (pass == 0) ? R1 : R0;
    const float* tb = (pass == 0) ? t1 : t0;

    // uvd = d * (Mq (u,v,1)) + c
    // Mq = K Rb Ra^T Ki (rows 0/1 pre-scaled by W/(W-1), H/(H-1)),
    // c  = K (tb - Rb Ra^T ta), Ki = [[s,0,-320s],[0,s,-240s],[0,0,1]], s=1/500.
    const float* A = Ra + b * 9;
    const float* Bm = Rb + b * 9;
    float N_[9];  // N = Rb * Ra^T
    #pragma unroll
    for (int i = 0; i < 3; ++i)
        #pragma unroll
        for (int jj = 0; jj < 3; ++jj)
            N_[i*3+jj] = Bm[i*3+0]*A[jj*3+0] + Bm[i*3+1]*A[jj*3+1] + Bm[i*3+2]*A[jj*3+2];
    float tax=ta[b*3+0], tay=ta[b*3+1], taz=ta[b*3+2];
    float qx_ = tb[b*3+0] - (N_[0]*tax + N_[1]*tay + N_[2]*taz);
    float qy_ = tb[b*3+1] - (N_[3]*tax + N_[4]*tay + N_[5]*taz);
    float qz_ = tb[b*3+2] - (N_[6]*tax + N_[7]*tay + N_[8]*taz);
    float M_[9];
    #pragma unroll
    for (int i = 0; i < 3; ++i)
        #pragma unroll
        for (int jj = 0; jj < 3; ++jj)
            M_[i*3+jj] = Km[i*3+0]*N_[0*3+jj] + Km[i*3+1]*N_[1*3+jj] + Km[i*3+2]*N_[2*3+jj];
    float cx = Km[0]*qx_ + Km[1]*qy_ + Km[2]*qz_;
    float cy = Km[3]*qx_ + Km[4]*qy_ + Km[5]*qz_;
    float cz = Km[6]*qx_ + Km[7]*qy_ + Km[8]*qz_;

    const float s_ = 1.0f / 500.0f;
    const float cwf = (float)WW / (float)(WW - 1);
    const float chf = (float)HH / (float)(HH - 1);
    float Mq[9];
    #pragma unroll
    for (int i = 0; i < 3; ++i) {
        float r0 = M_[i*3+0] * s_;
        float r1 = M_[i*3+1] * s_;
        float r2 = M_[i*3+0] * (-320.0f * s_) + M_[i*3+1] * (-240.0f * s_) + M_[i*3+2];
        float sc = (i == 0) ? cwf : (i == 1) ? chf : 1.0f;
        Mq[i*3+0] = r0 * sc; Mq[i*3+1] = r1 * sc; Mq[i*3+2] = r2 * sc;
    }
    float cxs = cx * cwf, cys = cy * chf;

    // coalesced source depth: 8 floats
    const float4* dp = (const float4*)(Ds + (size_t)b * NPIX + n0);
    float4 da = dp[0], db = dp[1];
    float dd[PPT] = {da.x, da.y, da.z, da.w, db.x, db.y, db.z, db.w};

    const float* img = Dt + (size_t)b * NPIX;

    // Preload the 6 border pairs a corner-clamped lane can touch:
    // rows {0,1,479} x col-pairs {0-1, 638-639}. Wave-uniform -> cheap.
    vf2 pTL = ((const uf2*)(img + 0))->v;
    vf2 pTR = ((const uf2*)(img + (WW - 2)))->v;
    vf2 pML = ((const uf2*)(img + WW))->v;
    vf2 pMR = ((const uf2*)(img + WW + (WW - 2)))->v;
    vf2 pBL = ((const uf2*)(img + (size_t)(HH - 1) * WW))->v;
    vf2 pBR = ((const uf2*)(img + (size_t)(HH - 1) * WW + (WW - 2)))->v;

    const int vrow = n0 / WW;            // all PPT px in same row (W % PPT == 0)
    const float fv = (float)vrow;
    const float fu0 = (float)(n0 - vrow * WW);

    // hoist the v-dependent part of the projection
    float bxv = fmaf(Mq[1], fv, Mq[2]);
    float byv = fmaf(Mq[4], fv, Mq[5]);
    float bzv = fmaf(Mq[7], fv, Mq[8]);

    float ud[PPT], wxs[PPT], wyf[PPT];
    int base[PPT], dy1[PPT];
    bool crn[PPT];
    vf2 top[PPT], bot[PPT];

    #pragma unroll
    for (int i = 0; i < PPT; ++i) {
        float fu = fu0 + (float)i;
        float mrx = fmaf(Mq[0], fu, bxv);
        float mry = fmaf(Mq[3], fu, byv);
        float mrz = fmaf(Mq[6], fu, bzv);
        float ux = fmaf(dd[i], mrx, cxs);
        float uy = fmaf(dd[i], mry, cys);
        float uu = fmaf(dd[i], mrz, cz);
        ud[i] = uu;

        float inv = __builtin_amdgcn_rcpf(fmaxf(uu, 0.0f) + 1e-12f);
        float sx = fmaf(ux, inv, -0.5f);
        float sy = fmaf(uy, inv, -0.5f);
        sx = fminf(fmaxf(sx, 0.0f), (float)(WW - 1));
        sy = fminf(fmaxf(sy, 0.0f), (float)(HH - 1));
        float fx0 = floorf(sx);
        float fy0 = floorf(sy);
        float wxf = sx - fx0;
        wyf[i] = sy - fy0;
        int x0 = (int)fx0;
        int y0 = (int)fy0;
        // Pair-load trick: one dwordx2 fetches {img[p], img[p+1]}.
        // x0==W-1 implies wxf==0; shift window left 1, force weight 1.0.
        int atEdge = (x0 == WW - 1);
        base[i] = y0 * WW + x0 - atEdge;
        wxs[i] = atEdge ? 1.0f : wxf;
        dy1[i] = (y0 < HH - 1) ? WW : 0;

        // Corner classification (conservative, exactness-safe):
        // uu<=0 -> inv=1e12; |ux|>1 -> |ux*inv| >> W so sx clamps to an
        // x-extreme; same for y. Then wxs is exactly {0,1}, wyf exactly 0,
        // and the 2x2 footprint is one of the preloaded border pairs.
        bool xs = ux > 0.0f;
        bool ys = uy > 0.0f;
        crn[i] = (uu <= 0.0f) && (fabsf(ux) > 1.0f) && (fabsf(uy) > 1.0f);
        if (crn[i]) {
            top[i] = ys ? (xs ? pBR : pBL) : (xs ? pTR : pTL);
            bot[i] = ys ? (xs ? pBR : pBL) : (xs ? pMR : pML);
        }
    }

    #pragma unroll
    for (int i = 0; i < PPT; ++i) {
        if (!crn[i]) {
            top[i] = ((const uf2*)(img + base[i]))->v;            // {v00, v01}
            bot[i] = ((const uf2*)(img + base[i] + dy1[i]))->v;   // {v10, v11}
        }
    }

    float diff = 0.0f;
    #pragma unroll
    for (int i = 0; i < PPT; ++i) {
        float tv = top[i].x + wxs[i] * (top[i].y - top[i].x);
        float bv = bot[i].x + wxs[i] * (bot[i].y - bot[i].x);
        float s = tv + wyf[i] * (bv - tv);
        diff += fabsf(ud[i] - s);
    }

    for (int off = 32; off > 0; off >>= 1)
        diff += __shfl_down(diff, off, 64);

    __shared__ float partial[BLK / 64];
    const int wave = threadIdx.x >> 6;
    const int lane = threadIdx.x & 63;
    if (lane == 0) partial[wave] = diff;
    __syncthreads();
    if (threadIdx.x == 0) {
        float s = partial[0] + partial[1] + partial[2] + partial[3];
        partials[blockIdx.x + GX * (blockIdx.y + BB * blockIdx.z)] = s;
    }
}

__global__ __launch_bounds__(1024) void reduce_partials_kernel(
    const float* __restrict__ partials, float* __restrict__ out)
{
    float s = 0.0f;
    for (int i = threadIdx.x; i < NPART; i += 1024) s += partials[i];
    for (int off = 32; off > 0; off >>= 1)
        s += __shfl_down(s, off, 64);
    __shared__ float partial[16];
    const int wave = threadIdx.x >> 6;
    const int lane = threadIdx.x & 63;
    if (lane == 0) partial[wave] = s;
    __syncthreads();
    if (threadIdx.x == 0) {
        float tot = 0.0f;
        #pragma unroll
        for (int i = 0; i < 16; ++i) tot += partial[i];
        out[0] = tot * (1.0f / (float)((long long)BB * NPIX));
    }
}

extern "C" void kernel_launch(void* const* d_in, const int* in_sizes, int n_in,
                              void* d_out, int out_size, void* d_ws, size_t ws_size,
                              hipStream_t stream) {
    const float* depth0 = (const float*)d_in[0];
    const float* depth1 = (const float*)d_in[1];
    const float* R0     = (const float*)d_in[2];
    const float* t0     = (const float*)d_in[3];
    const float* R1     = (const float*)d_in[4];
    const float* t1     = (const float*)d_in[5];
    const float* Km     = (const float*)d_in[6];
    float* out = (float*)d_out;
    float* partials = (float*)d_ws;

    dim3 grid(GX, BB, 2);
    proj_depth_loss_kernel<<<grid, dim3(BLK), 0, stream>>>(
        depth0, depth1, R0, t0, R1, t1, Km, partials);
    reduce_partials_kernel<<<1, 1024, 0, stream>>>(partials, out);
}